// Round 16
// baseline (176.483 us; speedup 1.0000x reference)
//
#include <hip/hip_runtime.h>
#include <hip/hip_bf16.h>

typedef unsigned short u16;
typedef unsigned int u32;
typedef __attribute__((ext_vector_type(8))) short bf16x8;
typedef __attribute__((ext_vector_type(4))) float f32x4;
typedef __attribute__((ext_vector_type(4))) unsigned short u16x4;
typedef __attribute__((ext_vector_type(2))) unsigned int u32x2;

static constexpr int TSEQ = 512;
static constexpr int NSEQ = 128;      // B*F
static constexpr int NTOK = NSEQ * TSEQ;

__device__ __forceinline__ float bf2f(u16 u) {
  u32 i = ((u32)u) << 16; float f; __builtin_memcpy(&f, &i, 4); return f;
}
__device__ __forceinline__ u16 f2bf(float f) {
  u32 u; __builtin_memcpy(&u, &f, 4);
  return (u16)((u + 0x7FFFu + ((u >> 16) & 1u)) >> 16);
}
__device__ __forceinline__ f32x4 mfma16(bf16x8 a, bf16x8 b, f32x4 c) {
  return __builtin_amdgcn_mfma_f32_16x16x32_bf16(a, b, c, 0, 0, 0);
}
__device__ __forceinline__ void gload_lds16(const u16* g, u16* l) {
  __builtin_amdgcn_global_load_lds((const __attribute__((address_space(1))) void*)g,
                                   (__attribute__((address_space(3))) void*)l, 16, 0, 0);
}
__device__ __forceinline__ float gelu_t(float v) {
  float uu = 0.7978845608f * (v + 0.044715f * v * v * v);
  return v / (1.f + __expf(-2.f * uu));
}

// -------- K0: weight conversion + rope tables + W2 column-mean (cm) --------
__global__ void k0_prep(const float* __restrict__ Wqkv, const float* __restrict__ Wo,
                        const float* __restrict__ W1, const float* __restrict__ W2,
                        const float* __restrict__ b2,
                        u16* __restrict__ Wqkv_b, u16* __restrict__ Wo_b,
                        u16* __restrict__ W1_b, float* __restrict__ cm,
                        float* __restrict__ b2m,
                        float* __restrict__ rc, float* __restrict__ rs) {
  int i = blockIdx.x * 256 + threadIdx.x;
  if (i < 49152) Wqkv_b[i] = f2bf(Wqkv[i]);
  if (i < 16384) Wo_b[i] = f2bf(Wo[i]);
  if (i < 65536) W1_b[i] = f2bf(W1[i]);
  if (i < 512) {           // cm[h] = mean_d W2[d,h]  (FFN2 collapses into this)
    float s = 0.f;
    for (int d = 0; d < 128; ++d) s += W2[d * 512 + i];
    cm[i] = s * (1.f / 128.f);
  }
  if (i == 0) {
    float s = 0.f;
    for (int d = 0; d < 128; ++d) s += b2[d];
    *b2m = s * (1.f / 128.f);
  }
  if (i < 8192) {
    int t = i >> 4, fi = i & 15;
    float inv = powf(10000.f, -(float)(2 * fi) / 32.f);
    float ang = (float)t * inv;
    rc[i] = cosf(ang); rs[i] = sinf(ang);
  }
}

// ------- K1: fused outer-product embed + LN1 + RoPE (1 wave = 1 token) -------
__global__ void k1_embed(const float* __restrict__ x, const float* __restrict__ W_in,
                         const float* __restrict__ b_in,
                         const float* __restrict__ g1, const float* __restrict__ be1,
                         u16* __restrict__ hcf, u16* __restrict__ h1, u16* __restrict__ qk,
                         const float* __restrict__ rc, const float* __restrict__ rs) {
  int w = threadIdx.x >> 6, l = threadIdx.x & 63;
  int n = blockIdx.x * 4 + w;
  int t = n & (TSEQ - 1), seq = n >> 9;
  int f = seq & 31, b = seq >> 5;
  float xv = x[((b << 9) + t) * 32 + f];
  int d0 = l * 2;
  float v0 = xv * W_in[d0 * 32 + f] + b_in[d0];
  float v1 = xv * W_in[(d0 + 1) * 32 + f] + b_in[d0 + 1];
  float s = v0 + v1, ss = v0 * v0 + v1 * v1;
  #pragma unroll
  for (int m = 1; m < 64; m <<= 1) { s += __shfl_xor(s, m); ss += __shfl_xor(ss, m); }
  float mean = s * (1.f / 128.f);
  float var = ss * (1.f / 128.f) - mean * mean;
  float rstd = rsqrtf(var + 1e-5f);
  float a0 = (v0 - mean) * rstd * g1[d0] + be1[d0];
  float a1 = (v1 - mean) * rstd * g1[d0 + 1] + be1[d0 + 1];
  ((u32*)hcf)[n * 64 + l] = (u32)f2bf(v0) | ((u32)f2bf(v1) << 16);
  ((u32*)h1)[n * 64 + l]  = (u32)f2bf(a0) | ((u32)f2bf(a1) << 16);
  float c = rc[t * 16 + (l & 15)], sn = rs[t * 16 + (l & 15)];
  float re = a0 * c - a1 * sn, ro = a0 * sn + a1 * c;
  ((u32*)qk)[n * 64 + l] = (u32)f2bf(re) | ((u32)f2bf(ro) << 16);
}

// -------- QKV GEMM v2: one block per 128 tokens; stage qk+h1 tiles ONCE,
// then 3 sequential panels (Q,K from Aq; V from Ah). 512 thr (8 waves), each
// wave owns a 16-token sub-tile; swapped mfma(W,A) C^T epilogue, u16x4 stores.
__global__ __launch_bounds__(512, 4)
void gemm_qkv(const u16* __restrict__ QKin, const u16* __restrict__ H1,
              const u16* __restrict__ Wqkv, const float* __restrict__ bqkv,
              u16* __restrict__ QKb, u16* __restrict__ Vb) {
  __shared__ u16 Aq[128 * 128];
  __shared__ u16 Ah[128 * 128];
  const int tid = threadIdx.x, l = tid & 63, w = tid >> 6;
  const int lr = l & 15, lg = l >> 4;
  const int m0 = blockIdx.x * 128;
  const int wb = __builtin_amdgcn_readfirstlane(tid & 0x1C0);

  #pragma unroll
  for (int it = 0; it < 4; ++it) {
    int ci = it * 512 + tid;
    int row = ci >> 4, p = ci & 15;
    size_t goff = (size_t)(m0 + row) * 128 + ((p ^ (row & 7)) << 3);
    gload_lds16(QKin + goff, Aq + (size_t)(it * 512 + wb) * 8);
    gload_lds16(H1 + goff, Ah + (size_t)(it * 512 + wb) * 8);
  }
  __syncthreads();

  const int tok = w * 16 + lr;          // tok&7 == lr&7
  #pragma unroll 1
  for (int ph = 0; ph < 3; ++ph) {
    const u16* As = (ph == 2) ? Ah : Aq;
    f32x4 acc[8];
    #pragma unroll
    for (int j = 0; j < 8; ++j) acc[j] = (f32x4){0.f, 0.f, 0.f, 0.f};
    #pragma unroll
    for (int kc = 0; kc < 4; ++kc) {
      bf16x8 af = *(const bf16x8*)(As + (tok * 16 + ((kc * 4 + lg) ^ (lr & 7))) * 8);
      #pragma unroll
      for (int ni = 0; ni < 8; ++ni) {
        bf16x8 wf = *(const bf16x8*)(Wqkv + (size_t)(ph * 128 + ni * 16 + lr) * 128
                                     + kc * 32 + lg * 8);
        acc[ni] = mfma16(wf, af, acc[ni]);
      }
    }
    const float* bias = bqkv + ph * 128;
    u16* C = (ph == 2) ? Vb : QKb;
    const int ldc = (ph == 2) ? 128 : 256;
    const int ccol = (ph == 1) ? 128 : 0;
    int token = m0 + tok;
    #pragma unroll
    for (int ni = 0; ni < 8; ++ni) {
      int nc0 = ni * 16 + lg * 4;
      f32x4 bs = *(const f32x4*)(bias + nc0);
      u16x4 qv;
      #pragma unroll
      for (int r = 0; r < 4; ++r) qv[r] = f2bf(acc[ni][r] + bs[r]);
      *(u16x4*)(C + (size_t)token * ldc + ccol + nc0) = qv;
    }
    __builtin_amdgcn_sched_barrier(0);
  }
}

// ---- fused Wo+LN+FFN: h2 = hcf + o@Wo^T + bo (regs); h2mean,h3 -> LDS;
// yout = h2mean + b2mean + sum_h cm[h]*gelu(W1·h3+b1)[h].  h3 never hits HBM.
// 512 thr (8 waves), 2 blocks/CU (71KB LDS), whole grid resident in one round.
__global__ __launch_bounds__(512, 4)
void wo_ln_ffn(const u16* __restrict__ OB, const u16* __restrict__ Wo_b,
               const float* __restrict__ bo, const u16* __restrict__ HCF,
               const float* __restrict__ g2, const float* __restrict__ be2,
               const u16* __restrict__ W1b, const float* __restrict__ b1,
               const float* __restrict__ cm, const float* __restrict__ b2m,
               float* __restrict__ yout) {
  __shared__ u16 At[128 * 128];     // obuf tile (swizzled linear)
  __shared__ u16 Ht[128 * 136];     // h3 tile, padded (272B row stride)
  __shared__ float Yp[128 * 8];
  __shared__ float Hm[128];
  const int tid = threadIdx.x, l = tid & 63, w = tid >> 6;
  const int lr = l & 15, lg = l >> 4;
  const int m0 = blockIdx.x * 128;
  const int wb = __builtin_amdgcn_readfirstlane(tid & 0x1C0);

  #pragma unroll
  for (int it = 0; it < 4; ++it) {
    int ci = it * 512 + tid;
    int row = ci >> 4, p = ci & 15;
    gload_lds16(OB + (size_t)(m0 + row) * 128 + ((p ^ (row & 7)) << 3),
                At + (size_t)(it * 512 + wb) * 8);
  }
  __syncthreads();

  // --- Wo GEMM: wave's 16 tokens x 128 cols ---
  const int tok = w * 16 + lr;
  f32x4 acc[8];
  #pragma unroll
  for (int j = 0; j < 8; ++j) acc[j] = (f32x4){0.f, 0.f, 0.f, 0.f};
  #pragma unroll
  for (int kc = 0; kc < 4; ++kc) {
    bf16x8 af = *(const bf16x8*)(At + (tok * 16 + ((kc * 4 + lg) ^ (lr & 7))) * 8);
    #pragma unroll
    for (int ni = 0; ni < 8; ++ni) {
      bf16x8 wf = *(const bf16x8*)(Wo_b + (size_t)(ni * 16 + lr) * 128 + kc * 32 + lg * 8);
      acc[ni] = mfma16(wf, af, acc[ni]);
    }
  }
  // --- residual + LN -> h2mean (LDS) + h3 (LDS) ---
  int token = m0 + tok;
  float sm = 0.f, sq = 0.f;
  #pragma unroll
  for (int ni = 0; ni < 8; ++ni) {
    int nc0 = ni * 16 + lg * 4;
    f32x4 bs = *(const f32x4*)(bo + nc0);
    u16x4 rv = *(const u16x4*)(HCF + (size_t)token * 128 + nc0);
    #pragma unroll
    for (int r = 0; r < 4; ++r) {
      float v = acc[ni][r] + bs[r] + bf2f(rv[r]);
      acc[ni][r] = v;
      sm += v; sq += v * v;
    }
  }
  sm += __shfl_xor(sm, 16); sq += __shfl_xor(sq, 16);
  sm += __shfl_xor(sm, 32); sq += __shfl_xor(sq, 32);
  float mean = sm * (1.f / 128.f);
  float var = sq * (1.f / 128.f) - mean * mean;
  float rstd = rsqrtf(var + 1e-5f);
  if (lg == 0) Hm[tok] = mean;
  #pragma unroll
  for (int ni = 0; ni < 8; ++ni) {
    int nc0 = ni * 16 + lg * 4;
    f32x4 gm = *(const f32x4*)(g2 + nc0);
    f32x4 bt = *(const f32x4*)(be2 + nc0);
    u16x4 qv;
    #pragma unroll
    for (int r = 0; r < 4; ++r)
      qv[r] = f2bf((acc[ni][r] - mean) * rstd * gm[r] + bt[r]);
    *(u16x4*)(Ht + tok * 136 + nc0) = qv;
  }
  __syncthreads();

  // --- FFN (v7 body): wave owns 64 hidden rows over 4 passes ---
  float yacc[8] = {0.f, 0.f, 0.f, 0.f, 0.f, 0.f, 0.f, 0.f};
  #pragma unroll 1
  for (int p = 0; p < 4; ++p) {
    const int hb = (p * 8 + w) * 16;
    const u16* wr = W1b + (size_t)(hb + lr) * 128 + lg * 8;
    bf16x8 wf0 = *(const bf16x8*)(wr);
    bf16x8 wf1 = *(const bf16x8*)(wr + 32);
    bf16x8 wf2 = *(const bf16x8*)(wr + 64);
    bf16x8 wf3 = *(const bf16x8*)(wr + 96);
    f32x4 cmv = *(const f32x4*)(cm + hb + lg * 4);
    f32x4 bsv = *(const f32x4*)(b1 + hb + lg * 4);
    #pragma unroll
    for (int tt = 0; tt < 8; ++tt) {
      const u16* ar = Ht + (tt * 16 + lr) * 136 + lg * 8;
      f32x4 a = (f32x4){0.f, 0.f, 0.f, 0.f};
      a = mfma16(wf0, *(const bf16x8*)(ar), a);
      a = mfma16(wf1, *(const bf16x8*)(ar + 32), a);
      a = mfma16(wf2, *(const bf16x8*)(ar + 64), a);
      a = mfma16(wf3, *(const bf16x8*)(ar + 96), a);
      #pragma unroll
      for (int r = 0; r < 4; ++r)
        yacc[tt] += cmv[r] * gelu_t(a[r] + bsv[r]);
    }
    __builtin_amdgcn_sched_barrier(0);
  }

  #pragma unroll
  for (int tt = 0; tt < 8; ++tt) {
    float p = yacc[tt];
    p += __shfl_xor(p, 16);
    p += __shfl_xor(p, 32);
    if (lg == 0) Yp[(tt * 16 + lr) * 8 + w] = p;
  }
  __syncthreads();
  if (tid < 128) {
    float s = 0.f;
    #pragma unroll
    for (int ww = 0; ww < 8; ++ww) s += Yp[tid * 8 + ww];
    yout[m0 + tid] = Hm[tid] + b2m[0] + s;
  }
}

// ---------------- MFMA windowed attention (unchanged) ----------------
__global__ __launch_bounds__(256, 4)
void attn_mfma(const u16* __restrict__ QK, const u16* __restrict__ V, u16* __restrict__ O) {
  __shared__ u16 Ks[192 * 32];
  __shared__ u16 Vt[32 * 192];
  __shared__ u16 Pl[4][16 * 96];
  const int qstart = blockIdx.x * 128, seq = blockIdx.y, h = blockIdx.z;
  const int tid = threadIdx.x, w = tid >> 6, l = tid & 63;
  const int lr = l & 15, lg = l >> 4;
  const size_t base = (size_t)seq * TSEQ;

  #pragma unroll
  for (int it = 0; it < 3; ++it) {
    int idx = it * 256 + tid;
    int kl = idx >> 2, c = idx & 3;
    int kg = qstart - 64 + kl; if (kg < 0) kg = 0;
    bf16x8 kv = *(const bf16x8*)(QK + (base + kg) * 256 + 128 + h * 32 + c * 8);
    int pc = c ^ ((kl >> 1) & 3);
    *(bf16x8*)(Ks + kl * 32 + pc * 8) = kv;
    bf16x8 vv = *(const bf16x8*)(V + (base + kg) * 128 + h * 32 + c * 8);
    #pragma unroll
    for (int j = 0; j < 8; ++j) {
      int hd = c * 8 + j;
      int f = ((hd & 7) ^ (hd >> 3)) & 7;
      Vt[hd * 192 + (((kl >> 3) ^ f) * 8) + (kl & 7)] = (u16)vv[j];
    }
  }
  __syncthreads();

  const float scale = 0.17677669529663687f;
  for (int qt = 0; qt < 2; ++qt) {
    const int klbase = (w * 2 + qt) * 16;
    const int t0 = qstart + klbase;
    bf16x8 qf = *(const bf16x8*)(QK + (base + t0 + lr) * 256 + h * 32 + lg * 8);
    f32x4 s[5];
    #pragma unroll
    for (int kt = 0; kt < 5; ++kt) {
      int key = klbase + kt * 16 + lr;
      int pc = lg ^ ((key >> 1) & 3);
      bf16x8 kf = *(const bf16x8*)(Ks + key * 32 + pc * 8);
      s[kt] = mfma16(kf, qf, (f32x4){0.f, 0.f, 0.f, 0.f});
    }
    float m = -1e30f;
    #pragma unroll
    for (int kt = 0; kt < 5; ++kt)
      #pragma unroll
      for (int r = 0; r < 4; ++r) {
        int kl = kt * 16 + lg * 4 + r;
        bool valid = (kl >= lr) && (kl <= lr + 64) && (kl >= 64 - t0);
        float sv = valid ? s[kt][r] * scale : -1e30f;
        s[kt][r] = sv;
        m = fmaxf(m, sv);
      }
    m = fmaxf(m, __shfl_xor(m, 16));
    m = fmaxf(m, __shfl_xor(m, 32));
    float sum = 0.f;
    #pragma unroll
    for (int kt = 0; kt < 5; ++kt)
      #pragma unroll
      for (int r = 0; r < 4; ++r) { float p = __expf(s[kt][r] - m); s[kt][r] = p; sum += p; }
    sum += __shfl_xor(sum, 16);
    sum += __shfl_xor(sum, 32);
    float rinv = 1.f / sum;
    u16* P = Pl[w];
    #pragma unroll
    for (int kt = 0; kt < 5; ++kt) {
      u32 lo = (u32)f2bf(s[kt][0] * rinv) | ((u32)f2bf(s[kt][1] * rinv) << 16);
      u32 hi = (u32)f2bf(s[kt][2] * rinv) | ((u32)f2bf(s[kt][3] * rinv) << 16);
      int u = 2 * kt + (lg >> 1);
      int up = (u & ~3) | ((u & 3) ^ (lr & 3));
      *(u32x2*)(P + lr * 96 + up * 8 + (lg & 1) * 4) = (u32x2){lo, hi};
    }
    {
      int u = 10 + (lg >> 1);
      int up = (u & ~3) | ((u & 3) ^ (lr & 3));
      *(u32x2*)(P + lr * 96 + up * 8 + (lg & 1) * 4) = (u32x2){0u, 0u};
    }
    f32x4 acc[2] = {{0.f,0.f,0.f,0.f},{0.f,0.f,0.f,0.f}};
    #pragma unroll
    for (int c = 0; c < 3; ++c) {
      int u = 4 * c + (lg ^ (lr & 3));
      bf16x8 pf = *(const bf16x8*)(P + lr * 96 + u * 8);
      #pragma unroll
      for (int n = 0; n < 2; ++n) {
        int hd = n * 16 + lr;
        int f = ((hd & 7) ^ (hd >> 3)) & 7;
        int uv = (klbase >> 3) + 4 * c + lg; if (uv > 23) uv = 23;
        bf16x8 vf = *(const bf16x8*)(Vt + hd * 192 + ((uv ^ f) * 8));
        acc[n] = mfma16(pf, vf, acc[n]);
      }
    }
    #pragma unroll
    for (int n = 0; n < 2; ++n)
      #pragma unroll
      for (int r = 0; r < 4; ++r)
        O[(base + t0 + lg * 4 + r) * 128 + h * 32 + n * 16 + lr] = f2bf(acc[n][r]);
  }
}

// ------------- K7: y_proj + final sum, 1 wave = one (b,t) position -------------
__global__ void k7_out(const float* __restrict__ x, const float* __restrict__ W_in,
                       const float* __restrict__ b_in, const float* __restrict__ Wout,
                       const float* __restrict__ bout, const float* __restrict__ yout,
                       float* __restrict__ out) {
  __shared__ float mids[4][128];
  int w = threadIdx.x >> 6, l = threadIdx.x & 63;
  int p = blockIdx.x * 4 + w;
  int b = p >> 9, t = p & 511;
  const float* xr = x + (size_t)p * 32;
  float m0 = b_in[2 * l], m1 = b_in[2 * l + 1];
  #pragma unroll
  for (int f = 0; f < 32; ++f) {
    float xv = xr[f];
    m0 += xv * W_in[(2 * l) * 32 + f];
    m1 += xv * W_in[(2 * l + 1) * 32 + f];
  }
  mids[w][2 * l] = m0; mids[w][2 * l + 1] = m1;
  __syncthreads();
  if (l < 32) {
    float a = bout[l];
    #pragma unroll 16
    for (int dd = 0; dd < 128; ++dd) a += mids[w][dd] * Wout[l * 128 + dd];
    float yo = yout[((b * 32 + l) << 9) + t];
    out[(size_t)p * 32 + l] = xr[l] + yo + a;
  }
}

extern "C" void kernel_launch(void* const* d_in, const int* in_sizes, int n_in,
                              void* d_out, int out_size, void* d_ws, size_t ws_size,
                              hipStream_t stream) {
  const float* x    = (const float*)d_in[0];
  const float* W_in = (const float*)d_in[1];
  const float* b_in = (const float*)d_in[2];
  const float* g1   = (const float*)d_in[3];
  const float* be1  = (const float*)d_in[4];
  const float* g2   = (const float*)d_in[5];
  const float* be2  = (const float*)d_in[6];
  const float* Wqkv = (const float*)d_in[7];
  const float* bqkv = (const float*)d_in[8];
  const float* Wo   = (const float*)d_in[9];
  const float* bo   = (const float*)d_in[10];
  const float* W1   = (const float*)d_in[11];
  const float* b1   = (const float*)d_in[12];
  const float* W2   = (const float*)d_in[13];
  const float* b2   = (const float*)d_in[14];
  const float* Wout = (const float*)d_in[15];
  const float* bout = (const float*)d_in[16];
  float* out = (float*)d_out;

  char* ws = (char*)d_ws;
  size_t off = 0;
  auto alloc = [&](size_t bytes) -> void* {
    void* p = ws + off; off += (bytes + 1023) & ~(size_t)1023; return p;
  };
  float* rc     = (float*)alloc(512 * 16 * 4);
  float* rs     = (float*)alloc(512 * 16 * 4);
  u16* Wqkv_b   = (u16*)alloc(49152 * 2);
  u16* Wo_b     = (u16*)alloc(16384 * 2);
  u16* W1_b     = (u16*)alloc(65536 * 2);
  float* cm     = (float*)alloc(512 * 4);
  float* b2m    = (float*)alloc(4);
  float* yout   = (float*)alloc((size_t)NTOK * 4);
  u16* hcf      = (u16*)alloc((size_t)NTOK * 128 * 2);
  u16* obuf     = (u16*)alloc((size_t)NTOK * 128 * 2);
  u16* h1       = (u16*)alloc((size_t)NTOK * 128 * 2);
  u16* qk       = (u16*)alloc((size_t)NTOK * 128 * 2);
  u16* QKb      = (u16*)alloc((size_t)NTOK * 256 * 2);
  u16* Vb       = (u16*)alloc((size_t)NTOK * 128 * 2);

  k0_prep<<<dim3(256), dim3(256), 0, stream>>>(Wqkv, Wo, W1, W2, b2,
                                               Wqkv_b, Wo_b, W1_b, cm, b2m, rc, rs);
  k1_embed<<<dim3(NTOK / 4), dim3(256), 0, stream>>>(x, W_in, b_in, g1, be1, hcf, h1, qk, rc, rs);
  // Q,K,V in one 512-block dispatch; qk+h1 tiles staged once per block
  gemm_qkv<<<dim3(512), dim3(512), 0, stream>>>(qk, h1, Wqkv_b, bqkv, QKb, Vb);
  attn_mfma<<<dim3(4, 128, 4), dim3(256), 0, stream>>>(QKb, Vb, obuf);
  // h2/h3/h2mean in regs+LDS only; yout = h2mean + b2mean + cm·gelu(W1·h3+b1)
  wo_ln_ffn<<<dim3(512), dim3(512), 0, stream>>>(obuf, Wo_b, bo, hcf, g2, be2,
                                                 W1_b, b1, cm, b2m, yout);
  k7_out<<<dim3(512), dim3(256), 0, stream>>>(x, W_in, b_in, Wout, bout, yout, out);
}

// Round 17
// 143.728 us; speedup vs baseline: 1.2279x; 1.2279x over previous
//
#include <hip/hip_runtime.h>
#include <hip/hip_bf16.h>

typedef unsigned short u16;
typedef unsigned int u32;
typedef __attribute__((ext_vector_type(8))) short bf16x8;
typedef __attribute__((ext_vector_type(4))) float f32x4;
typedef __attribute__((ext_vector_type(4))) unsigned short u16x4;
typedef __attribute__((ext_vector_type(2))) unsigned int u32x2;

static constexpr int TSEQ = 512;
static constexpr int NSEQ = 128;      // B*F
static constexpr int NTOK = NSEQ * TSEQ;

__device__ __forceinline__ float bf2f(u16 u) {
  u32 i = ((u32)u) << 16; float f; __builtin_memcpy(&f, &i, 4); return f;
}
__device__ __forceinline__ u16 f2bf(float f) {
  u32 u; __builtin_memcpy(&u, &f, 4);
  return (u16)((u + 0x7FFFu + ((u >> 16) & 1u)) >> 16);
}
__device__ __forceinline__ f32x4 mfma16(bf16x8 a, bf16x8 b, f32x4 c) {
  return __builtin_amdgcn_mfma_f32_16x16x32_bf16(a, b, c, 0, 0, 0);
}
__device__ __forceinline__ void gload_lds16(const u16* g, u16* l) {
  __builtin_amdgcn_global_load_lds((const __attribute__((address_space(1))) void*)g,
                                   (__attribute__((address_space(3))) void*)l, 16, 0, 0);
}
__device__ __forceinline__ float gelu_t(float v) {
  float uu = 0.7978845608f * (v + 0.044715f * v * v * v);
  return v / (1.f + __expf(-2.f * uu));
}

// -------- K0: weight conversion + rope tables + W2 column-mean (cm) --------
__global__ void k0_prep(const float* __restrict__ Wqkv, const float* __restrict__ Wo,
                        const float* __restrict__ W1, const float* __restrict__ W2,
                        const float* __restrict__ b2,
                        u16* __restrict__ Wqkv_b, u16* __restrict__ Wo_b,
                        u16* __restrict__ W1_b, float* __restrict__ cm,
                        float* __restrict__ b2m,
                        float* __restrict__ rc, float* __restrict__ rs) {
  int i = blockIdx.x * 256 + threadIdx.x;
  if (i < 49152) Wqkv_b[i] = f2bf(Wqkv[i]);
  if (i < 16384) Wo_b[i] = f2bf(Wo[i]);
  if (i < 65536) W1_b[i] = f2bf(W1[i]);
  if (i < 512) {           // cm[h] = mean_d W2[d,h]  (FFN2 collapses into this)
    float s = 0.f;
    for (int d = 0; d < 128; ++d) s += W2[d * 512 + i];
    cm[i] = s * (1.f / 128.f);
  }
  if (i == 0) {
    float s = 0.f;
    for (int d = 0; d < 128; ++d) s += b2[d];
    *b2m = s * (1.f / 128.f);
  }
  if (i < 8192) {
    int t = i >> 4, fi = i & 15;
    float inv = powf(10000.f, -(float)(2 * fi) / 32.f);
    float ang = (float)t * inv;
    rc[i] = cosf(ang); rs[i] = sinf(ang);
  }
}

// ------- K1: fused outer-product embed + LN1 + RoPE (1 wave = 1 token) -------
__global__ void k1_embed(const float* __restrict__ x, const float* __restrict__ W_in,
                         const float* __restrict__ b_in,
                         const float* __restrict__ g1, const float* __restrict__ be1,
                         u16* __restrict__ hcf, u16* __restrict__ h1, u16* __restrict__ qk,
                         const float* __restrict__ rc, const float* __restrict__ rs) {
  int w = threadIdx.x >> 6, l = threadIdx.x & 63;
  int n = blockIdx.x * 4 + w;
  int t = n & (TSEQ - 1), seq = n >> 9;
  int f = seq & 31, b = seq >> 5;
  float xv = x[((b << 9) + t) * 32 + f];
  int d0 = l * 2;
  float v0 = xv * W_in[d0 * 32 + f] + b_in[d0];
  float v1 = xv * W_in[(d0 + 1) * 32 + f] + b_in[d0 + 1];
  float s = v0 + v1, ss = v0 * v0 + v1 * v1;
  #pragma unroll
  for (int m = 1; m < 64; m <<= 1) { s += __shfl_xor(s, m); ss += __shfl_xor(ss, m); }
  float mean = s * (1.f / 128.f);
  float var = ss * (1.f / 128.f) - mean * mean;
  float rstd = rsqrtf(var + 1e-5f);
  float a0 = (v0 - mean) * rstd * g1[d0] + be1[d0];
  float a1 = (v1 - mean) * rstd * g1[d0 + 1] + be1[d0 + 1];
  ((u32*)hcf)[n * 64 + l] = (u32)f2bf(v0) | ((u32)f2bf(v1) << 16);
  ((u32*)h1)[n * 64 + l]  = (u32)f2bf(a0) | ((u32)f2bf(a1) << 16);
  float c = rc[t * 16 + (l & 15)], sn = rs[t * 16 + (l & 15)];
  float re = a0 * c - a1 * sn, ro = a0 * sn + a1 * c;
  ((u32*)qk)[n * 64 + l] = (u32)f2bf(re) | ((u32)f2bf(ro) << 16);
}

// -------- QKV GEMM v3 (N-split waves): one block per 128 tokens; stage qk+h1
// ONCE; wave w owns col-tile w (16 cols) of EACH panel (Q,K,V) -> Wqkv read
// exactly once per block (96 KB, was 768 KB in v2). Per phase: 4 hoisted wf +
// per-token-tile 4-chained MFMA + immediate u16x4 store (live set ~30 VGPR).
__global__ __launch_bounds__(512, 4)
void gemm_qkv(const u16* __restrict__ QKin, const u16* __restrict__ H1,
              const u16* __restrict__ Wqkv, const float* __restrict__ bqkv,
              u16* __restrict__ QKb, u16* __restrict__ Vb) {
  __shared__ u16 Aq[128 * 128];
  __shared__ u16 Ah[128 * 128];
  const int tid = threadIdx.x, l = tid & 63, w = tid >> 6;
  const int lr = l & 15, lg = l >> 4;
  const int m0 = blockIdx.x * 128;
  const int wb = __builtin_amdgcn_readfirstlane(tid & 0x1C0);

  #pragma unroll
  for (int it = 0; it < 4; ++it) {
    int ci = it * 512 + tid;
    int row = ci >> 4, p = ci & 15;
    size_t goff = (size_t)(m0 + row) * 128 + ((p ^ (row & 7)) << 3);
    gload_lds16(QKin + goff, Aq + (size_t)(it * 512 + wb) * 8);
    gload_lds16(H1 + goff, Ah + (size_t)(it * 512 + wb) * 8);
  }
  __syncthreads();

  #pragma unroll 1
  for (int ph = 0; ph < 3; ++ph) {
    const u16* As = (ph == 2) ? Ah : Aq;
    const int wrow = ph * 128 + w * 16;               // wave's 16 W-rows (out cols)
    const u16* wr = Wqkv + (size_t)(wrow + lr) * 128 + lg * 8;
    bf16x8 wf0 = *(const bf16x8*)(wr);
    bf16x8 wf1 = *(const bf16x8*)(wr + 32);
    bf16x8 wf2 = *(const bf16x8*)(wr + 64);
    bf16x8 wf3 = *(const bf16x8*)(wr + 96);
    f32x4 bs = *(const f32x4*)(bqkv + wrow + lg * 4);
    u16* C = (ph == 2) ? Vb : QKb;
    const int ldc = (ph == 2) ? 128 : 256;
    const int ccol = ((ph == 2) ? 0 : ph * 128) + w * 16 + lg * 4;
    #pragma unroll
    for (int tt = 0; tt < 8; ++tt) {
      const int tok = tt * 16 + lr;
      const u16* ar = As + (tok * 16) * 8;
      f32x4 a = (f32x4){0.f, 0.f, 0.f, 0.f};
      a = mfma16(wf0, *(const bf16x8*)(ar + (((0 * 4 + lg) ^ (lr & 7)) << 3)), a);
      a = mfma16(wf1, *(const bf16x8*)(ar + (((1 * 4 + lg) ^ (lr & 7)) << 3)), a);
      a = mfma16(wf2, *(const bf16x8*)(ar + (((2 * 4 + lg) ^ (lr & 7)) << 3)), a);
      a = mfma16(wf3, *(const bf16x8*)(ar + (((3 * 4 + lg) ^ (lr & 7)) << 3)), a);
      u16x4 qv;
      #pragma unroll
      for (int r = 0; r < 4; ++r) qv[r] = f2bf(a[r] + bs[r]);
      *(u16x4*)(C + (size_t)(m0 + tok) * ldc + ccol) = qv;
    }
    __builtin_amdgcn_sched_barrier(0);
  }
}

// ---- fused Wo+LN+FFN: h2 = hcf + o@Wo^T + bo (regs); h2mean,h3 -> LDS;
// yout = h2mean + b2mean + sum_h cm[h]*gelu(W1·h3+b1)[h].  h3 never hits HBM.
__global__ __launch_bounds__(512, 4)
void wo_ln_ffn(const u16* __restrict__ OB, const u16* __restrict__ Wo_b,
               const float* __restrict__ bo, const u16* __restrict__ HCF,
               const float* __restrict__ g2, const float* __restrict__ be2,
               const u16* __restrict__ W1b, const float* __restrict__ b1,
               const float* __restrict__ cm, const float* __restrict__ b2m,
               float* __restrict__ yout) {
  __shared__ u16 At[128 * 128];     // obuf tile (swizzled linear)
  __shared__ u16 Ht[128 * 136];     // h3 tile, padded (272B row stride)
  __shared__ float Yp[128 * 8];
  __shared__ float Hm[128];
  const int tid = threadIdx.x, l = tid & 63, w = tid >> 6;
  const int lr = l & 15, lg = l >> 4;
  const int m0 = blockIdx.x * 128;
  const int wb = __builtin_amdgcn_readfirstlane(tid & 0x1C0);

  #pragma unroll
  for (int it = 0; it < 4; ++it) {
    int ci = it * 512 + tid;
    int row = ci >> 4, p = ci & 15;
    gload_lds16(OB + (size_t)(m0 + row) * 128 + ((p ^ (row & 7)) << 3),
                At + (size_t)(it * 512 + wb) * 8);
  }
  __syncthreads();

  // --- Wo GEMM: wave's 16 tokens x 128 cols ---
  const int tok = w * 16 + lr;
  f32x4 acc[8];
  #pragma unroll
  for (int j = 0; j < 8; ++j) acc[j] = (f32x4){0.f, 0.f, 0.f, 0.f};
  #pragma unroll
  for (int kc = 0; kc < 4; ++kc) {
    bf16x8 af = *(const bf16x8*)(At + (tok * 16 + ((kc * 4 + lg) ^ (lr & 7))) * 8);
    #pragma unroll
    for (int ni = 0; ni < 8; ++ni) {
      bf16x8 wf = *(const bf16x8*)(Wo_b + (size_t)(ni * 16 + lr) * 128 + kc * 32 + lg * 8);
      acc[ni] = mfma16(wf, af, acc[ni]);
    }
  }
  // --- residual + LN -> h2mean (LDS) + h3 (LDS) ---
  int token = m0 + tok;
  float sm = 0.f, sq = 0.f;
  #pragma unroll
  for (int ni = 0; ni < 8; ++ni) {
    int nc0 = ni * 16 + lg * 4;
    f32x4 bs = *(const f32x4*)(bo + nc0);
    u16x4 rv = *(const u16x4*)(HCF + (size_t)token * 128 + nc0);
    #pragma unroll
    for (int r = 0; r < 4; ++r) {
      float v = acc[ni][r] + bs[r] + bf2f(rv[r]);
      acc[ni][r] = v;
      sm += v; sq += v * v;
    }
  }
  sm += __shfl_xor(sm, 16); sq += __shfl_xor(sq, 16);
  sm += __shfl_xor(sm, 32); sq += __shfl_xor(sq, 32);
  float mean = sm * (1.f / 128.f);
  float var = sq * (1.f / 128.f) - mean * mean;
  float rstd = rsqrtf(var + 1e-5f);
  if (lg == 0) Hm[tok] = mean;
  #pragma unroll
  for (int ni = 0; ni < 8; ++ni) {
    int nc0 = ni * 16 + lg * 4;
    f32x4 gm = *(const f32x4*)(g2 + nc0);
    f32x4 bt = *(const f32x4*)(be2 + nc0);
    u16x4 qv;
    #pragma unroll
    for (int r = 0; r < 4; ++r)
      qv[r] = f2bf((acc[ni][r] - mean) * rstd * gm[r] + bt[r]);
    *(u16x4*)(Ht + tok * 136 + nc0) = qv;
  }
  __syncthreads();

  // --- FFN (v7 body): wave owns 64 hidden rows over 4 passes ---
  float yacc[8] = {0.f, 0.f, 0.f, 0.f, 0.f, 0.f, 0.f, 0.f};
  #pragma unroll 1
  for (int p = 0; p < 4; ++p) {
    const int hb = (p * 8 + w) * 16;
    const u16* wr = W1b + (size_t)(hb + lr) * 128 + lg * 8;
    bf16x8 wf0 = *(const bf16x8*)(wr);
    bf16x8 wf1 = *(const bf16x8*)(wr + 32);
    bf16x8 wf2 = *(const bf16x8*)(wr + 64);
    bf16x8 wf3 = *(const bf16x8*)(wr + 96);
    f32x4 cmv = *(const f32x4*)(cm + hb + lg * 4);
    f32x4 bsv = *(const f32x4*)(b1 + hb + lg * 4);
    #pragma unroll
    for (int tt = 0; tt < 8; ++tt) {
      const u16* ar = Ht + (tt * 16 + lr) * 136 + lg * 8;
      f32x4 a = (f32x4){0.f, 0.f, 0.f, 0.f};
      a = mfma16(wf0, *(const bf16x8*)(ar), a);
      a = mfma16(wf1, *(const bf16x8*)(ar + 32), a);
      a = mfma16(wf2, *(const bf16x8*)(ar + 64), a);
      a = mfma16(wf3, *(const bf16x8*)(ar + 96), a);
      #pragma unroll
      for (int r = 0; r < 4; ++r)
        yacc[tt] += cmv[r] * gelu_t(a[r] + bsv[r]);
    }
    __builtin_amdgcn_sched_barrier(0);
  }

  #pragma unroll
  for (int tt = 0; tt < 8; ++tt) {
    float p = yacc[tt];
    p += __shfl_xor(p, 16);
    p += __shfl_xor(p, 32);
    if (lg == 0) Yp[(tt * 16 + lr) * 8 + w] = p;
  }
  __syncthreads();
  if (tid < 128) {
    float s = 0.f;
    #pragma unroll
    for (int ww = 0; ww < 8; ++ww) s += Yp[tid * 8 + ww];
    yout[m0 + tid] = Hm[tid] + b2m[0] + s;
  }
}

// ---------------- MFMA windowed attention (unchanged) ----------------
__global__ __launch_bounds__(256, 4)
void attn_mfma(const u16* __restrict__ QK, const u16* __restrict__ V, u16* __restrict__ O) {
  __shared__ u16 Ks[192 * 32];
  __shared__ u16 Vt[32 * 192];
  __shared__ u16 Pl[4][16 * 96];
  const int qstart = blockIdx.x * 128, seq = blockIdx.y, h = blockIdx.z;
  const int tid = threadIdx.x, w = tid >> 6, l = tid & 63;
  const int lr = l & 15, lg = l >> 4;
  const size_t base = (size_t)seq * TSEQ;

  #pragma unroll
  for (int it = 0; it < 3; ++it) {
    int idx = it * 256 + tid;
    int kl = idx >> 2, c = idx & 3;
    int kg = qstart - 64 + kl; if (kg < 0) kg = 0;
    bf16x8 kv = *(const bf16x8*)(QK + (base + kg) * 256 + 128 + h * 32 + c * 8);
    int pc = c ^ ((kl >> 1) & 3);
    *(bf16x8*)(Ks + kl * 32 + pc * 8) = kv;
    bf16x8 vv = *(const bf16x8*)(V + (base + kg) * 128 + h * 32 + c * 8);
    #pragma unroll
    for (int j = 0; j < 8; ++j) {
      int hd = c * 8 + j;
      int f = ((hd & 7) ^ (hd >> 3)) & 7;
      Vt[hd * 192 + (((kl >> 3) ^ f) * 8) + (kl & 7)] = (u16)vv[j];
    }
  }
  __syncthreads();

  const float scale = 0.17677669529663687f;
  for (int qt = 0; qt < 2; ++qt) {
    const int klbase = (w * 2 + qt) * 16;
    const int t0 = qstart + klbase;
    bf16x8 qf = *(const bf16x8*)(QK + (base + t0 + lr) * 256 + h * 32 + lg * 8);
    f32x4 s[5];
    #pragma unroll
    for (int kt = 0; kt < 5; ++kt) {
      int key = klbase + kt * 16 + lr;
      int pc = lg ^ ((key >> 1) & 3);
      bf16x8 kf = *(const bf16x8*)(Ks + key * 32 + pc * 8);
      s[kt] = mfma16(kf, qf, (f32x4){0.f, 0.f, 0.f, 0.f});
    }
    float m = -1e30f;
    #pragma unroll
    for (int kt = 0; kt < 5; ++kt)
      #pragma unroll
      for (int r = 0; r < 4; ++r) {
        int kl = kt * 16 + lg * 4 + r;
        bool valid = (kl >= lr) && (kl <= lr + 64) && (kl >= 64 - t0);
        float sv = valid ? s[kt][r] * scale : -1e30f;
        s[kt][r] = sv;
        m = fmaxf(m, sv);
      }
    m = fmaxf(m, __shfl_xor(m, 16));
    m = fmaxf(m, __shfl_xor(m, 32));
    float sum = 0.f;
    #pragma unroll
    for (int kt = 0; kt < 5; ++kt)
      #pragma unroll
      for (int r = 0; r < 4; ++r) { float p = __expf(s[kt][r] - m); s[kt][r] = p; sum += p; }
    sum += __shfl_xor(sum, 16);
    sum += __shfl_xor(sum, 32);
    float rinv = 1.f / sum;
    u16* P = Pl[w];
    #pragma unroll
    for (int kt = 0; kt < 5; ++kt) {
      u32 lo = (u32)f2bf(s[kt][0] * rinv) | ((u32)f2bf(s[kt][1] * rinv) << 16);
      u32 hi = (u32)f2bf(s[kt][2] * rinv) | ((u32)f2bf(s[kt][3] * rinv) << 16);
      int u = 2 * kt + (lg >> 1);
      int up = (u & ~3) | ((u & 3) ^ (lr & 3));
      *(u32x2*)(P + lr * 96 + up * 8 + (lg & 1) * 4) = (u32x2){lo, hi};
    }
    {
      int u = 10 + (lg >> 1);
      int up = (u & ~3) | ((u & 3) ^ (lr & 3));
      *(u32x2*)(P + lr * 96 + up * 8 + (lg & 1) * 4) = (u32x2){0u, 0u};
    }
    f32x4 acc[2] = {{0.f,0.f,0.f,0.f},{0.f,0.f,0.f,0.f}};
    #pragma unroll
    for (int c = 0; c < 3; ++c) {
      int u = 4 * c + (lg ^ (lr & 3));
      bf16x8 pf = *(const bf16x8*)(P + lr * 96 + u * 8);
      #pragma unroll
      for (int n = 0; n < 2; ++n) {
        int hd = n * 16 + lr;
        int f = ((hd & 7) ^ (hd >> 3)) & 7;
        int uv = (klbase >> 3) + 4 * c + lg; if (uv > 23) uv = 23;
        bf16x8 vf = *(const bf16x8*)(Vt + hd * 192 + ((uv ^ f) * 8));
        acc[n] = mfma16(pf, vf, acc[n]);
      }
    }
    #pragma unroll
    for (int n = 0; n < 2; ++n)
      #pragma unroll
      for (int r = 0; r < 4; ++r)
        O[(base + t0 + lg * 4 + r) * 128 + h * 32 + n * 16 + lr] = f2bf(acc[n][r]);
  }
}

// ------------- K7: y_proj + final sum, 1 wave = one (b,t) position -------------
__global__ void k7_out(const float* __restrict__ x, const float* __restrict__ W_in,
                       const float* __restrict__ b_in, const float* __restrict__ Wout,
                       const float* __restrict__ bout, const float* __restrict__ yout,
                       float* __restrict__ out) {
  __shared__ float mids[4][128];
  int w = threadIdx.x >> 6, l = threadIdx.x & 63;
  int p = blockIdx.x * 4 + w;
  int b = p >> 9, t = p & 511;
  const float* xr = x + (size_t)p * 32;
  float m0 = b_in[2 * l], m1 = b_in[2 * l + 1];
  #pragma unroll
  for (int f = 0; f < 32; ++f) {
    float xv = xr[f];
    m0 += xv * W_in[(2 * l) * 32 + f];
    m1 += xv * W_in[(2 * l + 1) * 32 + f];
  }
  mids[w][2 * l] = m0; mids[w][2 * l + 1] = m1;
  __syncthreads();
  if (l < 32) {
    float a = bout[l];
    #pragma unroll 16
    for (int dd = 0; dd < 128; ++dd) a += mids[w][dd] * Wout[l * 128 + dd];
    float yo = yout[((b * 32 + l) << 9) + t];
    out[(size_t)p * 32 + l] = xr[l] + yo + a;
  }
}

extern "C" void kernel_launch(void* const* d_in, const int* in_sizes, int n_in,
                              void* d_out, int out_size, void* d_ws, size_t ws_size,
                              hipStream_t stream) {
  const float* x    = (const float*)d_in[0];
  const float* W_in = (const float*)d_in[1];
  const float* b_in = (const float*)d_in[2];
  const float* g1   = (const float*)d_in[3];
  const float* be1  = (const float*)d_in[4];
  const float* g2   = (const float*)d_in[5];
  const float* be2  = (const float*)d_in[6];
  const float* Wqkv = (const float*)d_in[7];
  const float* bqkv = (const float*)d_in[8];
  const float* Wo   = (const float*)d_in[9];
  const float* bo   = (const float*)d_in[10];
  const float* W1   = (const float*)d_in[11];
  const float* b1   = (const float*)d_in[12];
  const float* W2   = (const float*)d_in[13];
  const float* b2   = (const float*)d_in[14];
  const float* Wout = (const float*)d_in[15];
  const float* bout = (const float*)d_in[16];
  float* out = (float*)d_out;

  char* ws = (char*)d_ws;
  size_t off = 0;
  auto alloc = [&](size_t bytes) -> void* {
    void* p = ws + off; off += (bytes + 1023) & ~(size_t)1023; return p;
  };
  float* rc     = (float*)alloc(512 * 16 * 4);
  float* rs     = (float*)alloc(512 * 16 * 4);
  u16* Wqkv_b   = (u16*)alloc(49152 * 2);
  u16* Wo_b     = (u16*)alloc(16384 * 2);
  u16* W1_b     = (u16*)alloc(65536 * 2);
  float* cm     = (float*)alloc(512 * 4);
  float* b2m    = (float*)alloc(4);
  float* yout   = (float*)alloc((size_t)NTOK * 4);
  u16* hcf      = (u16*)alloc((size_t)NTOK * 128 * 2);
  u16* obuf     = (u16*)alloc((size_t)NTOK * 128 * 2);
  u16* h1       = (u16*)alloc((size_t)NTOK * 128 * 2);
  u16* qk       = (u16*)alloc((size_t)NTOK * 128 * 2);
  u16* QKb      = (u16*)alloc((size_t)NTOK * 256 * 2);
  u16* Vb       = (u16*)alloc((size_t)NTOK * 128 * 2);

  k0_prep<<<dim3(256), dim3(256), 0, stream>>>(Wqkv, Wo, W1, W2, b2,
                                               Wqkv_b, Wo_b, W1_b, cm, b2m, rc, rs);
  k1_embed<<<dim3(NTOK / 4), dim3(256), 0, stream>>>(x, W_in, b_in, g1, be1, hcf, h1, qk, rc, rs);
  // Q,K,V in one 512-block dispatch; qk+h1 staged once; Wqkv read once/block
  gemm_qkv<<<dim3(512), dim3(512), 0, stream>>>(qk, h1, Wqkv_b, bqkv, QKb, Vb);
  attn_mfma<<<dim3(4, 128, 4), dim3(256), 0, stream>>>(QKb, Vb, obuf);
  // h2/h3/h2mean in regs+LDS only; yout = h2mean + b2mean + cm·gelu(W1·h3+b1)
  wo_ln_ffn<<<dim3(512), dim3(512), 0, stream>>>(obuf, Wo_b, bo, hcf, g2, be2,
                                                 W1_b, b1, cm, b2m, yout);
  k7_out<<<dim3(512), dim3(256), 0, stream>>>(x, W_in, b_in, Wout, bout, yout, out);
}